// Round 1
// 65.360 us; speedup vs baseline: 1.1274x; 1.1274x over previous
//
#include <hip/hip_runtime.h>
#include <math.h>

// Problem constants (reference: pos [64,1024,3] fp32, rad=0.15)
#define TN     64
#define NP     1024
#define RADIUS 0.15f
#define MIN_D  (2.0f * RADIUS)
#define R2     (MIN_D * MIN_D)

#define BLOCK  512                 // 8 waves per block
#define WAVES  (BLOCK / 64)
#define SPLIT  8                   // blocks per timestep -> 512 blocks = 2/CU, 16 waves/CU
#define GI     16                  // i-rows register-tiled per wave-group
#define NGRP   (NP / GI)           // 64 groups per timestep = SPLIT blocks x 8 waves
#define NBLK   (TN * SPLIT)        // 512 blocks
#define PPT    (NP / BLOCK)        // 2 points binned per thread

// x-axis bins: width 1/3.3 = 0.30303 > MIN_D (0.3), so colliding pairs are
// always in same-or-adjacent bins; pairs >=2 bins apart have dx > 0.30302
// and can never pass d2 < R2. Pruning is exact; d2 test is unchanged fp32.
#define NB     40
#define XMIN   (-6.0f)
#define INVW   3.3f

__launch_bounds__(BLOCK, 4)   // 4 waves/EU -> 2 blocks/CU, VGPR cap 128
__global__ void collide_kernel(const float* __restrict__ pos,
                               double* __restrict__ partial) {
    __shared__ float         shin[NP * 3];   // raw staged xyz (interleaved)
    __shared__ float         shs [NP * 3];   // bin-sorted xyz (interleaved)
    __shared__ unsigned int  hist[NB];       // bin counts (then consumed by scan)
    __shared__ unsigned int  S[NB + 1];      // exclusive bin starts; S[NB] = 1024
    __shared__ unsigned char sbin[NP];       // bin id per sorted point

    const int t     = blockIdx.x / SPLIT;
    const int split = blockIdx.x % SPLIT;
    const int tid   = threadIdx.x;
    const int lane  = tid & 63;
    const int wave  = tid >> 6;

    // ---- stage timestep slice: 768 float4 ----
    const float4* p4  = (const float4*)(pos + (size_t)t * NP * 3);
    float4*       sh4 = (float4*)shin;
    for (int i = tid; i < NP * 3 / 4; i += BLOCK) sh4[i] = p4[i];
    if (tid < NB) hist[tid] = 0u;
    __syncthreads();

    // ---- bin + within-bin rank via LDS atomics (2 pts/thread) ----
    int          bq[PPT];
    unsigned int rq[PPT];
    #pragma unroll
    for (int q = 0; q < PPT; ++q) {
        const int p = tid + q * BLOCK;
        const float x = shin[3 * p];
        int b = (int)((x - XMIN) * INVW);
        b = b < 0 ? 0 : (b > NB - 1 ? NB - 1 : b);
        bq[q] = b;
        rq[q] = atomicAdd(&hist[b], 1u);
    }
    __syncthreads();

    // ---- exclusive scan of bin counts (first wave, shfl) ----
    if (tid < 64) {
        unsigned int c    = (tid < NB) ? hist[tid] : 0u;
        unsigned int incl = c;
        #pragma unroll
        for (int d = 1; d < 64; d <<= 1) {
            const unsigned int y = __shfl_up(incl, d, 64);
            if (lane >= d) incl += y;
        }
        if (tid < NB) S[tid + 1] = incl;
        if (tid == 0) S[0] = 0u;
    }
    __syncthreads();

    // ---- scatter into bin-sorted order ----
    #pragma unroll
    for (int q = 0; q < PPT; ++q) {
        const int p = tid + q * BLOCK;
        const unsigned int dst = S[bq[q]] + rq[q];
        shs[3 * dst + 0] = shin[3 * p + 0];
        shs[3 * dst + 1] = shin[3 * p + 1];
        shs[3 * dst + 2] = shin[3 * p + 2];
        sbin[dst] = (unsigned char)bq[q];
    }
    __syncthreads();

    // ---- per-wave group sweep with adjacent-bin cutoff ----
    unsigned int cnt  = 0;
    double       loss = 0.0;
    {
        const int g = wave * SPLIT + split;   // bijective over 64 groups/timestep
        const int b = g * GI;

        float xi[GI], yi[GI], zi[GI];
        #pragma unroll
        for (int k = 0; k < GI; ++k) {        // same-address reads: LDS broadcast
            xi[k] = shs[3 * (b + k) + 0];
            yi[k] = shs[3 * (b + k) + 1];
            zi[k] = shs[3 * (b + k) + 2];
        }
        // Opaque barrier: pins the 48-value i-tile into VGPRs so the allocator
        // cannot rematerialize from LDS inside the j-loop (observed failure
        // mode: VGPR=32, ~56 lane-ops/pair instead of ~9).
        #pragma unroll
        for (int k = 0; k < GI; ++k)
            asm volatile("" : "+v"(xi[k]), "+v"(yi[k]), "+v"(zi[k]));

        // j-range cutoff: all pairs for this tile lie in j <= end of bin(last_i)+1
        const int bb   = (int)sbin[b + GI - 1];
        const int jend = (int)S[(bb + 2 <= NB) ? (bb + 2) : NB];

        // head: in-tile pairs, one lane per j (lanes 0..14)
        if (lane < GI - 1) {
            const int j = b + 1 + lane;
            const float xj = shs[3 * j], yj = shs[3 * j + 1], zj = shs[3 * j + 2];
            #pragma unroll
            for (int k = 0; k < GI; ++k) {
                if (k <= lane) {                       // i = b+k < j
                    const float dx = xi[k] - xj;
                    const float dy = yi[k] - yj;
                    const float dz = zi[k] - zj;
                    const float d2 = dx * dx + dy * dy + dz * dz;
                    if (d2 < R2) {
                        cnt++;
                        const float pen = MIN_D - __builtin_amdgcn_sqrtf(d2);
                        loss += (double)(pen * pen);
                    }
                }
            }
        }

        // tail: j in [b+GI, jend), 64-lane stride (ranges are ~130 long now)
        for (int j = b + GI + lane; j < jend; j += 64) {
            const float xj = shs[3 * j], yj = shs[3 * j + 1], zj = shs[3 * j + 2];
            #pragma unroll
            for (int k = 0; k < GI; ++k) {
                const float dx = xi[k] - xj;
                const float dy = yi[k] - yj;
                const float dz = zi[k] - zj;
                const float d2 = dx * dx + dy * dy + dz * dz;
                const bool hit = d2 < R2;
                cnt += hit ? 1u : 0u;                  // v_cmp + v_addc, no branch
                if (hit) {                             // rare (~0.25%)
                    const float pen = MIN_D - __builtin_amdgcn_sqrtf(d2);
                    loss += (double)(pen * pen);
                }
            }
        }
    }

    // ---- reduction: wave shuffle, then cross-wave via LDS ----
    float fcnt = (float)cnt;
    #pragma unroll
    for (int off = 32; off > 0; off >>= 1) {
        fcnt += __shfl_down(fcnt, off);
        loss += __shfl_down(loss, off);
    }
    __shared__ double cs[WAVES], ls[WAVES];
    if (lane == 0) { cs[wave] = (double)fcnt; ls[wave] = loss; }
    __syncthreads();
    if (tid == 0) {
        double c = 0.0, l = 0.0;
        #pragma unroll
        for (int w = 0; w < WAVES; ++w) { c += cs[w]; l += ls[w]; }
        partial[2 * blockIdx.x + 0] = c;   // unconditional store: no init needed
        partial[2 * blockIdx.x + 1] = l;
    }
}

__global__ void finalize_kernel(const double* __restrict__ partial,
                                float* __restrict__ out) {
    const int tid = threadIdx.x;          // 256 threads
    double c = 0.0, l = 0.0;
    #pragma unroll
    for (int i = 0; i < NBLK / 256; ++i) {             // 2 double2 per thread
        const double2 p = ((const double2*)partial)[tid + i * 256];
        c += p.x;
        l += p.y;
    }
    #pragma unroll
    for (int off = 32; off > 0; off >>= 1) {
        c += __shfl_down(c, off);
        l += __shfl_down(l, off);
    }
    __shared__ double cs[4], ls[4];
    const int wave = tid >> 6;
    if ((tid & 63) == 0) { cs[wave] = c; ls[wave] = l; }
    __syncthreads();
    if (tid == 0) {
        double ct = 0.0, lt = 0.0;
        #pragma unroll
        for (int w = 0; w < 4; ++w) { ct += cs[w]; lt += ls[w]; }
        out[0] = (float)ct;   // count exact (< 2^24)
        out[1] = (float)lt;
    }
}

extern "C" void kernel_launch(void* const* d_in, const int* in_sizes, int n_in,
                              void* d_out, int out_size, void* d_ws, size_t ws_size,
                              hipStream_t stream) {
    const float* pos     = (const float*)d_in[0];
    double*      partial = (double*)d_ws;
    float*       out     = (float*)d_out;

    collide_kernel<<<NBLK, BLOCK, 0, stream>>>(pos, partial);
    finalize_kernel<<<1, 256, 0, stream>>>(partial, out);
}

// Round 3
// 63.514 us; speedup vs baseline: 1.1601x; 1.0291x over previous
//
#include <hip/hip_runtime.h>
#include <math.h>

// Problem constants (reference: pos [64,1024,3] fp32, rad=0.15)
#define TN     64
#define NP     1024
#define RADIUS 0.15f
#define MIN_D  (2.0f * RADIUS)
#define R2     (MIN_D * MIN_D)

#define BLOCK  512                 // 8 waves per block
#define WAVES  (BLOCK / 64)
#define SPLIT  8                   // blocks per timestep -> 512 blocks = 2/CU, 16 waves/CU
#define GI     16                  // i-rows register-tiled per wave-group
#define NGRP   (NP / GI)           // 64 groups per timestep = SPLIT blocks x 8 waves
#define NBLK   (TN * SPLIT)        // 512 blocks
#define PPT    (NP / BLOCK)        // 2 points handled per thread in the sort phase

// x-axis bins: width 1/3.3 = 0.30303 > MIN_D (0.3), so colliding pairs are
// always in same-or-adjacent bins; pairs >=2 bins apart have dx > 0.30302
// even under fp rounding of the bin index (margin 3e-3 vs error ~5e-6).
// Clamping only merges outer bins -> strictly conservative. Pruning is exact.
#define NB     40
#define XMIN   (-6.0f)
#define INVW   3.3f

// Pinned d^2 association: identical instruction-level rounding in head, tail,
// and across recompiles (compiler may not re-associate explicit fmaf).
__device__ __forceinline__ float dist2(float dx, float dy, float dz) {
    return __builtin_fmaf(dx, dx, __builtin_fmaf(dy, dy, dz * dz));
}

__launch_bounds__(BLOCK, 4)   // 4 waves/EU -> 2 blocks/CU, VGPR cap 128
__global__ void collide_kernel(const float* __restrict__ pos,
                               float* __restrict__ partial) {
    __shared__ float         shs [NP * 3];   // bin-sorted xyz (interleaved)
    __shared__ unsigned int  hist[NB];       // bin counts
    __shared__ unsigned int  S[NB + 1];      // exclusive bin starts; S[NB] = 1024
    __shared__ unsigned char sbin[NP];       // bin id per sorted point

    const int t     = blockIdx.x / SPLIT;
    const int split = blockIdx.x % SPLIT;
    const int tid   = threadIdx.x;
    const int lane  = tid & 63;
    const int wave  = tid >> 6;

    // ---- load 2 points/thread straight to registers (768B/wave, L2-hot) ----
    const float* pt = pos + (size_t)t * NP * 3;
    float px[PPT], py[PPT], pz[PPT];
    int          bq[PPT];
    unsigned int rq[PPT];
    #pragma unroll
    for (int q = 0; q < PPT; ++q) {
        const int p = tid + q * BLOCK;
        px[q] = pt[3 * p + 0];
        py[q] = pt[3 * p + 1];
        pz[q] = pt[3 * p + 2];
    }
    if (tid < NB) hist[tid] = 0u;
    __syncthreads();

    // ---- bin + within-bin rank via LDS atomics ----
    #pragma unroll
    for (int q = 0; q < PPT; ++q) {
        int b = (int)((px[q] - XMIN) * INVW);
        b = b < 0 ? 0 : (b > NB - 1 ? NB - 1 : b);
        bq[q] = b;
        rq[q] = atomicAdd(&hist[b], 1u);
    }
    __syncthreads();

    // ---- exclusive scan of bin counts (first wave, shfl) ----
    if (tid < 64) {
        unsigned int c    = (tid < NB) ? hist[tid] : 0u;
        unsigned int incl = c;
        #pragma unroll
        for (int d = 1; d < 64; d <<= 1) {
            const unsigned int y = __shfl_up(incl, d, 64);
            if (lane >= d) incl += y;
        }
        if (tid < NB) S[tid + 1] = incl;
        if (tid == 0) S[0] = 0u;
    }
    __syncthreads();

    // ---- scatter registers into bin-sorted LDS order ----
    #pragma unroll
    for (int q = 0; q < PPT; ++q) {
        const unsigned int dst = S[bq[q]] + rq[q];   // unique by construction
        shs[3 * dst + 0] = px[q];
        shs[3 * dst + 1] = py[q];
        shs[3 * dst + 2] = pz[q];
        sbin[dst] = (unsigned char)bq[q];
    }
    __syncthreads();

    // ---- per-wave group sweep with adjacent-bin cutoff ----
    unsigned int cnt  = 0;
    float        loss = 0.0f;    // fp32 accumulation (round-0 numeric path)
    {
        const int g = wave * SPLIT + split;   // bijective over 64 groups/timestep
        const int b = g * GI;

        float xi[GI], yi[GI], zi[GI];
        #pragma unroll
        for (int k = 0; k < GI; ++k) {        // same-address reads: LDS broadcast
            xi[k] = shs[3 * (b + k) + 0];
            yi[k] = shs[3 * (b + k) + 1];
            zi[k] = shs[3 * (b + k) + 2];
        }
        // Opaque barrier: pins the 48-value i-tile into VGPRs so the allocator
        // cannot rematerialize from LDS inside the j-loop (observed failure
        // mode: VGPR=32, ~56 lane-ops/pair instead of ~9).
        #pragma unroll
        for (int k = 0; k < GI; ++k)
            asm volatile("" : "+v"(xi[k]), "+v"(yi[k]), "+v"(zi[k]));

        // j-range cutoff: sbin non-decreasing by construction; all pairs for
        // this tile lie in j < end of bin(last_i)+1.
        const int bb   = (int)sbin[b + GI - 1];
        const int jend = (int)S[(bb + 2 <= NB) ? (bb + 2) : NB];

        // head: in-tile pairs, one lane per j (lanes 0..14)
        if (lane < GI - 1) {
            const int j = b + 1 + lane;
            const float xj = shs[3 * j], yj = shs[3 * j + 1], zj = shs[3 * j + 2];
            #pragma unroll
            for (int k = 0; k < GI; ++k) {
                if (k <= lane) {                       // i = b+k < j
                    const float d2 = dist2(xi[k] - xj, yi[k] - yj, zi[k] - zj);
                    if (d2 < R2) {
                        cnt++;
                        const float pen = MIN_D - __builtin_amdgcn_sqrtf(d2);
                        loss += pen * pen;
                    }
                }
            }
        }

        // tail: j in [b+GI, jend), 64-lane stride (ranges ~100-250 long)
        for (int j = b + GI + lane; j < jend; j += 64) {
            const float xj = shs[3 * j], yj = shs[3 * j + 1], zj = shs[3 * j + 2];
            #pragma unroll
            for (int k = 0; k < GI; ++k) {
                const float d2 = dist2(xi[k] - xj, yi[k] - yj, zi[k] - zj);
                const bool hit = d2 < R2;
                cnt += hit ? 1u : 0u;                  // v_cmp + v_addc, no branch
                if (hit) {                             // rare (~0.25%)
                    const float pen = MIN_D - __builtin_amdgcn_sqrtf(d2);
                    loss += pen * pen;
                }
            }
        }
    }

    // ---- reduction: wave shuffle, then cross-wave via LDS (fp32) ----
    float fcnt = (float)cnt;
    #pragma unroll
    for (int off = 32; off > 0; off >>= 1) {
        fcnt += __shfl_down(fcnt, off);
        loss += __shfl_down(loss, off);
    }
    __shared__ float cs[WAVES], ls[WAVES];
    if (lane == 0) { cs[wave] = fcnt; ls[wave] = loss; }
    __syncthreads();
    if (tid == 0) {
        float c = 0.0f, l = 0.0f;
        #pragma unroll
        for (int w = 0; w < WAVES; ++w) { c += cs[w]; l += ls[w]; }
        partial[2 * blockIdx.x + 0] = c;   // unconditional store: no init needed
        partial[2 * blockIdx.x + 1] = l;
    }
}

__global__ void finalize_kernel(const float* __restrict__ partial,
                                float* __restrict__ out) {
    const int lane = threadIdx.x;          // 64 threads: single wave, no barrier
    float c = 0.0f, l = 0.0f;
    #pragma unroll
    for (int i = 0; i < NBLK / 64; ++i) {  // 8 float2 per lane
        const float2 p = ((const float2*)partial)[lane + i * 64];
        c += p.x;
        l += p.y;
    }
    #pragma unroll
    for (int off = 32; off > 0; off >>= 1) {
        c += __shfl_down(c, off);
        l += __shfl_down(l, off);
    }
    if (lane == 0) {
        out[0] = c;   // harness reads float32; count exact (< 2^24)
        out[1] = l;
    }
}

extern "C" void kernel_launch(void* const* d_in, const int* in_sizes, int n_in,
                              void* d_out, int out_size, void* d_ws, size_t ws_size,
                              hipStream_t stream) {
    const float* pos     = (const float*)d_in[0];
    float*       partial = (float*)d_ws;
    float*       out     = (float*)d_out;

    collide_kernel<<<NBLK, BLOCK, 0, stream>>>(pos, partial);
    finalize_kernel<<<1, 64, 0, stream>>>(partial, out);
}